// Round 1
// baseline (1682.839 us; speedup 1.0000x reference)
//
#include <hip/hip_runtime.h>
#include <hip/hip_bf16.h>

// BiDirectionalFusionModule on MI355X.
// All heavy convs = implicit GEMM, bf16 MFMA 16x16x32, f32 accumulate.
// Activations staged as zero-padded NHWC bf16. ~220MB workspace.

typedef __bf16 bf16x8 __attribute__((ext_vector_type(8)));
typedef float f32x4 __attribute__((ext_vector_type(4)));

#define DEVI __device__ __forceinline__

DEVI float bf2f(unsigned short u){
  union { unsigned int i; float f; } v; v.i = ((unsigned int)u) << 16; return v.f;
}
DEVI unsigned short f2bf(float f){
  union { float f; unsigned int i; } v; v.f = f;
  unsigned int x = v.i;
  unsigned int r = (x + 0x7fffu + ((x >> 16) & 1u)) >> 16;
  return (unsigned short)r;
}

// ---------------------------------------------------------------- BN prep
__global__ void bnprep_k(const float* __restrict__ g1, const float* __restrict__ be1,
                         const float* __restrict__ m1, const float* __restrict__ v1,
                         const float* __restrict__ b1,
                         const float* __restrict__ gf, const float* __restrict__ bef,
                         const float* __restrict__ mf, const float* __restrict__ vf,
                         const float* __restrict__ bf,
                         float* __restrict__ sc1, float* __restrict__ sh1,
                         float* __restrict__ scf, float* __restrict__ shf)
{
  int c = threadIdx.x;
  float s = g1[c] * rsqrtf(v1[c] + 1e-5f);
  sc1[c] = s; sh1[c] = (b1[c] - m1[c]) * s + be1[c];
  s = gf[c] * rsqrtf(vf[c] + 1e-5f);
  scf[c] = s; shf[c] = (bf[c] - mf[c]) * s + bef[c];
}

// ------------------------------------------------- NCHW f32 -> padded NHWC bf16
// Xpad layout: [8][90][90][512], ch 0..255 = rgb, 256..511 = depth. Borders pre-zeroed.
__global__ __launch_bounds__(256)
void prep_xpad_k(const float* __restrict__ rgb, const float* __restrict__ dep,
                 unsigned short* __restrict__ Xpad)
{
  __shared__ unsigned short tile[64][65];
  int bi = blockIdx.x;
  int b = bi / 968;
  int rem = bi - b * 968;
  int cblk = rem / 121;
  int pblk = rem - cblk * 121;
  int t = threadIdx.x;
  int pl = t & 63;
  #pragma unroll
  for (int pass = 0; pass < 16; ++pass){
    int cl = pass * 4 + (t >> 6);
    int c = cblk * 64 + cl;
    const float* sp = (c < 256) ? (rgb + ((size_t)b * 256 + c) * 7744)
                                : (dep + ((size_t)b * 256 + (c - 256)) * 7744);
    tile[cl][pl] = f2bf(sp[pblk * 64 + pl]);
  }
  __syncthreads();
  int cl2 = t & 63;
  for (int pass = 0; pass < 16; ++pass){
    int pl2 = pass * 4 + (t >> 6);
    int pixg = pblk * 64 + pl2;
    int y = pixg / 88, x = pixg - y * 88;
    Xpad[(((size_t)b * 90 + y + 1) * 90 + (x + 1)) * 512 + cblk * 64 + cl2] = tile[cl2][pl2];
  }
}

// ---------------------------------------------------------------- weight reshuffles
// dst [9][256co][512ci] from sm_w1 (256,512,3,3)
__global__ void prep_w1t_k(const float* __restrict__ w, unsigned short* __restrict__ o)
{
  int idx = blockIdx.x * 256 + threadIdx.x;        // 9<<17 total
  int tap = idx >> 17;
  int co = (idx >> 9) & 255;
  int ci = idx & 511;
  o[idx] = f2bf(w[((size_t)co * 512 + ci) * 9 + tap]);
}
// dst [9][256co][576ci] from fus_w (256,513,3,3); ci>=513 -> 0
__global__ void prep_wfus_k(const float* __restrict__ w, unsigned short* __restrict__ o)
{
  int idx = blockIdx.x * 256 + threadIdx.x;        // 9*256*576 total
  int ci = idx % 576;
  int rem = idx / 576;
  int co = rem & 255;
  int tap = rem >> 8;
  float v = (ci < 513) ? w[((size_t)co * 513 + ci) * 9 + tap] : 0.f;
  o[idx] = f2bf(v);
}
// dst [64][256co][256ci] from sr_w (256,256,8,8)
__global__ void prep_wsr_k(const float* __restrict__ w, unsigned short* __restrict__ o)
{
  int idx = blockIdx.x * 256 + threadIdx.x;        // 64*256*256 total
  int tap = idx >> 16;
  int co = (idx >> 8) & 255;
  int ci = idx & 255;
  o[idx] = f2bf(w[((size_t)co * 256 + ci) * 64 + tap]);
}

// ---------------------------------------------------------------- implicit GEMM
// C[n][co] = sum_{tap,ci} A[pixel(n,tap)][ci] * W[tap][co][ci]
// 128x128 tile, BK=64, 4 waves (2x2), mfma_f32_16x16x32_bf16, XOR-swizzled LDS.
struct GemmP {
  const unsigned short* A;
  const unsigned short* W;
  const float* ep_scale;
  const float* ep_shift;
  void* out;
  int img_px, row_px, px_el, ch_off, y0, x0;
  int tapw, stridepix, out_w, out_imgpx;
  int Cin, Mtot, Mtiles, Ntiles, k_per;
};

template<int EPI>   // 0: BN+ReLU -> bf16 NHWC[.][256]   1: BN+ReLU -> f32 NCHW   2: f32 partial [slot][968][256]
__global__ __launch_bounds__(256)
void gemm_k(GemmP p)
{
  __shared__ __bf16 As[128 * 64];
  __shared__ __bf16 Bs[128 * 64];
  const int t = threadIdx.x;
  const int lane = t & 63;
  const int wid = t >> 6;
  const int wr = wid >> 1, wc = wid & 1;

  int pid = blockIdx.x;
  int mt = pid % p.Mtiles;
  int nt = (pid / p.Mtiles) % p.Ntiles;
  int slot = pid / (p.Mtiles * p.Ntiles);
  int kb = slot * p.k_per;
  int nch = p.k_per / 64;

  long long apix[4]; int cbg8[4]; int wrow[4]; int lofs[4];
  #pragma unroll
  for (int i = 0; i < 4; ++i){
    int r = i * 32 + (t >> 3);
    cbg8[i] = ((t & 7) ^ (r & 7)) * 8;
    int n = mt * 128 + r;
    int nc = n < p.Mtot ? n : 0;
    int b = nc / p.out_imgpx; int rr = nc - b * p.out_imgpx;
    int yo = rr / p.out_w;    int xo = rr - yo * p.out_w;
    apix[i] = (long long)b * p.img_px + (long long)(yo * p.stridepix + p.y0) * p.row_px
            + (xo * p.stridepix + p.x0);
    wrow[i] = (nt * 128 + r) * p.Cin + cbg8[i];
    lofs[i] = r * 64 + (t & 7) * 8;
  }

  f32x4 acc[4][4];
  #pragma unroll
  for (int i = 0; i < 4; ++i)
    #pragma unroll
    for (int j = 0; j < 4; ++j)
      acc[i][j] = f32x4{0.f, 0.f, 0.f, 0.f};

  const long long wstap = 256LL * p.Cin;

  for (int ch = 0; ch < nch; ++ch){
    int kc = kb + ch * 64;
    int tap = kc / p.Cin;
    int cib = kc - tap * p.Cin;
    int dy = tap / p.tapw, dx = tap - dy * p.tapw;
    __syncthreads();
    #pragma unroll
    for (int i = 0; i < 4; ++i){
      long long aoff = (apix[i] + (long long)dy * p.row_px + dx) * p.px_el + p.ch_off + cib + cbg8[i];
      uint4 va = *reinterpret_cast<const uint4*>(p.A + aoff);
      *reinterpret_cast<uint4*>(&As[lofs[i]]) = va;
      long long woff = (long long)tap * wstap + wrow[i] + cib;
      uint4 vb = *reinterpret_cast<const uint4*>(p.W + woff);
      *reinterpret_cast<uint4*>(&Bs[lofs[i]]) = vb;
    }
    __syncthreads();
    #pragma unroll
    for (int ks = 0; ks < 2; ++ks){
      bf16x8 av[4], bv[4];
      #pragma unroll
      for (int mi = 0; mi < 4; ++mi){
        int ar = wr * 64 + mi * 16 + (lane & 15);
        int cb = (ks * 4 + (lane >> 4)) ^ (ar & 7);
        av[mi] = *reinterpret_cast<const bf16x8*>(&As[ar * 64 + cb * 8]);
      }
      #pragma unroll
      for (int ni = 0; ni < 4; ++ni){
        int br = wc * 64 + ni * 16 + (lane & 15);
        int cb = (ks * 4 + (lane >> 4)) ^ (br & 7);
        bv[ni] = *reinterpret_cast<const bf16x8*>(&Bs[br * 64 + cb * 8]);
      }
      #pragma unroll
      for (int mi = 0; mi < 4; ++mi)
        #pragma unroll
        for (int ni = 0; ni < 4; ++ni)
          acc[mi][ni] = __builtin_amdgcn_mfma_f32_16x16x32_bf16(av[mi], bv[ni], acc[mi][ni], 0, 0, 0);
    }
  }

  const int r0 = (lane >> 4) * 4;
  const int c0 = lane & 15;
  #pragma unroll
  for (int mi = 0; mi < 4; ++mi){
    int nbase = mt * 128 + wr * 64 + mi * 16 + r0;
    #pragma unroll
    for (int ni = 0; ni < 4; ++ni){
      int co = nt * 128 + wc * 64 + ni * 16 + c0;
      f32x4 a = acc[mi][ni];
      if constexpr (EPI == 0){
        float sc = p.ep_scale[co], sh = p.ep_shift[co];
        unsigned short* o = (unsigned short*)p.out;
        #pragma unroll
        for (int r = 0; r < 4; ++r){
          float v = fmaf(a[r], sc, sh); v = v > 0.f ? v : 0.f;
          o[(size_t)(nbase + r) * 256 + co] = f2bf(v);
        }
      } else if constexpr (EPI == 1){
        float sc = p.ep_scale[co], sh = p.ep_shift[co];
        float* o = (float*)p.out;
        int b = nbase / 7744; int s = nbase - b * 7744;
        float4 v;
        v.x = fmaxf(fmaf(a[0], sc, sh), 0.f);
        v.y = fmaxf(fmaf(a[1], sc, sh), 0.f);
        v.z = fmaxf(fmaf(a[2], sc, sh), 0.f);
        v.w = fmaxf(fmaf(a[3], sc, sh), 0.f);
        *reinterpret_cast<float4*>(o + ((size_t)(b * 256 + co)) * 7744 + s) = v;
      } else {
        float* o = (float*)p.out + (size_t)slot * 968 * 256;
        #pragma unroll
        for (int r = 0; r < 4; ++r){
          int n = nbase + r;
          if (n < p.Mtot) o[(size_t)n * 256 + co] = a[r];
        }
      }
    }
  }
}

// ---------------------------------------------------------------- spatial mask
__global__ __launch_bounds__(256)
void mask_k(const unsigned short* __restrict__ h1, const float* __restrict__ w2,
            const float* __restrict__ b2, float* __restrict__ mask,
            unsigned short* __restrict__ FusPad)
{
  __shared__ float w[256];
  int t = threadIdx.x;
  w[t] = w2[t];
  __syncthreads();
  int n = blockIdx.x * 256 + t;
  const unsigned short* row = h1 + (size_t)n * 256;
  float s = b2[0];
  for (int c = 0; c < 256; c += 8){
    union { uint4 v; unsigned short s_[8]; } u;
    u.v = *reinterpret_cast<const uint4*>(row + c);
    #pragma unroll
    for (int j = 0; j < 8; ++j) s = fmaf(bf2f(u.s_[j]), w[c + j], s);
  }
  float m = 1.f / (1.f + __expf(-s));
  mask[n] = m;
  int b = n / 7744, sr = n - b * 7744;
  int y = sr / 88, x = sr - y * 88;
  FusPad[(((size_t)b * 90 + y + 1) * 90 + (x + 1)) * 576 + 512] = f2bf(m);
}

// ---------------------------------------------------------------- f_depth * mask -> NHWC bf16 [61952][256]
__global__ __launch_bounds__(256)
void fdm_k(const unsigned short* __restrict__ Xpad, const float* __restrict__ mask,
           unsigned short* __restrict__ fdm)
{
  int idx = blockIdx.x * 256 + threadIdx.x;   // 61952*32
  int n = idx >> 5, cb = idx & 31;
  int b = n / 7744, s = n - b * 7744;
  int y = s / 88, x = s - y * 88;
  size_t pix = ((size_t)(b * 90 + y + 1)) * 90 + x + 1;
  union { uint4 v; unsigned short s_[8]; } u, w;
  u.v = *reinterpret_cast<const uint4*>(Xpad + pix * 512 + 256 + cb * 8);
  float m = mask[n];
  #pragma unroll
  for (int j = 0; j < 8; ++j) w.s_[j] = f2bf(bf2f(u.s_[j]) * m);
  *reinterpret_cast<uint4*>(fdm + (size_t)n * 256 + cb * 8) = w.v;
}

// ---------------------------------------------------------------- sum split-K partials + channel LN -> kvr bf16
__global__ __launch_bounds__(256)
void lnkvr_k(const float* __restrict__ part, const float* __restrict__ srb,
             const float* __restrict__ lng, const float* __restrict__ lnb,
             unsigned short* __restrict__ kvr)
{
  int n = blockIdx.x, t = threadIdx.x;
  float v = srb[t];
  for (int s = 0; s < 16; ++s) v += part[((size_t)s * 968 + n) * 256 + t];
  float s1 = v, s2 = v * v;
  #pragma unroll
  for (int o = 1; o < 64; o <<= 1){ s1 += __shfl_xor(s1, o, 64); s2 += __shfl_xor(s2, o, 64); }
  __shared__ float a1[4], a2[4];
  if ((t & 63) == 0){ a1[t >> 6] = s1; a2[t >> 6] = s2; }
  __syncthreads();
  float t1 = a1[0] + a1[1] + a1[2] + a1[3];
  float t2 = a2[0] + a2[1] + a2[2] + a2[3];
  float mean = t1 * (1.f / 256.f);
  float var = t2 * (1.f / 256.f) - mean * mean;
  float rstd = rsqrtf(var + 1e-5f);
  kvr[(size_t)n * 256 + t] = f2bf((v - mean) * rstd * lng[t] + lnb[t]);
}

// ---------------------------------------------------------------- 1x1 conv 256->32 (Q and K)
// mode 0: src = linear bf16 [n][256].  mode 1: src = Xpad interior, rgb channels.
__global__ __launch_bounds__(256)
void dotconv_k(const unsigned short* __restrict__ src, int mode,
               const float* __restrict__ w, const float* __restrict__ bias,
               float* __restrict__ out)
{
  const int t = threadIdx.x;
  const int n = blockIdx.x * 8 + (t >> 5);
  const int co = t & 31;
  const unsigned short* row;
  if (mode == 1){
    int b = n / 7744, s = n - b * 7744;
    int y = s / 88, x = s - y * 88;
    row = src + (((size_t)(b * 90 + y + 1)) * 90 + (x + 1)) * 512;
  } else {
    row = src + (size_t)n * 256;
  }
  float sum = bias[co];
  const float* wr = w + (size_t)co * 256;
  for (int c = 0; c < 256; c += 8){
    union { uint4 v; unsigned short s_[8]; } u;
    u.v = *reinterpret_cast<const uint4*>(row + c);
    #pragma unroll
    for (int j = 0; j < 8; ++j) sum = fmaf(bf2f(u.s_[j]), wr[c + j], sum);
  }
  out[(size_t)n * 32 + co] = sum;
}

// ---------------------------------------------------------------- 1x1 conv 256->256 (V)
__global__ __launch_bounds__(256)
void vconv_k(const unsigned short* __restrict__ kvr, const float* __restrict__ vw,
             const float* __restrict__ vb, unsigned short* __restrict__ V)
{
  __shared__ float rowf[256];
  const int n = blockIdx.x, t = threadIdx.x;
  rowf[t] = bf2f(kvr[(size_t)n * 256 + t]);
  __syncthreads();
  float sum = vb[t];
  const float* wr = vw + (size_t)t * 256;
  #pragma unroll 8
  for (int c = 0; c < 256; ++c) sum = fmaf(rowf[c], wr[c], sum);
  V[(size_t)n * 256 + t] = f2bf(sum);
}

// ---------------------------------------------------------------- fused attention + LN + residual
// Per block: 32 query rows of one image. KV = 121 positions (LDS).
// Writes enh = res + gamma*LN(attn_out) into FusPad channels [outChOff..outChOff+256).
__global__ __launch_bounds__(256)
void attn_k(const float* __restrict__ Qbuf, const float* __restrict__ Kbuf,
            const unsigned short* __restrict__ Vbuf,
            const unsigned short* __restrict__ Xpad, int resChOff,
            unsigned short* __restrict__ FusPad, int outChOff,
            const float* __restrict__ ng, const float* __restrict__ nbv,
            const float* __restrict__ gammap)
{
  __shared__ float Kt[121 * 33];
  __shared__ float Qt[32 * 33];
  __shared__ float Sl[32 * 124];
  __shared__ unsigned short Vt[121 * 256];
  const int t = threadIdx.x;
  const int nb0 = blockIdx.x * 32;
  const int b = nb0 / 7744;
  const int mbase = b * 121;

  {
    const float4* src = reinterpret_cast<const float4*>(Qbuf + (size_t)nb0 * 32);
    float4 v = src[t];
    int i = t >> 3, c = (t & 7) * 4;
    float* q = &Qt[i * 33 + c];
    q[0] = v.x; q[1] = v.y; q[2] = v.z; q[3] = v.w;
  }
  for (int idx = t; idx < 121 * 32; idx += 256){
    int m = idx >> 5, c = idx & 31;
    Kt[m * 33 + c] = Kbuf[(size_t)mbase * 32 + idx];
  }
  {
    const uint4* src = reinterpret_cast<const uint4*>(Vbuf + (size_t)mbase * 256);
    uint4* dst = reinterpret_cast<uint4*>(Vt);
    for (int idx = t; idx < 121 * 32; idx += 256) dst[idx] = src[idx];
  }
  __syncthreads();

  const float scale = 0.17677669529663687f;  // 32^-0.5
  for (int it = 0; it < 16; ++it){
    int idx = it * 256 + t;
    int n = idx >> 7, m = idx & 127;
    if (m < 121){
      const float* qp = &Qt[n * 33];
      const float* kp = &Kt[m * 33];
      float s = 0.f;
      #pragma unroll
      for (int c = 0; c < 32; ++c) s = fmaf(qp[c], kp[c], s);
      Sl[n * 124 + m] = s * scale;
    }
  }
  __syncthreads();

  const int n2 = t >> 3, sub = t & 7;
  float mx = -1e30f;
  for (int m = sub; m < 121; m += 8) mx = fmaxf(mx, Sl[n2 * 124 + m]);
  #pragma unroll
  for (int ofs = 1; ofs < 8; ofs <<= 1) mx = fmaxf(mx, __shfl_xor(mx, ofs, 64));
  float sum = 0.f;
  for (int m = sub; m < 121; m += 8){
    float pv = __expf(Sl[n2 * 124 + m] - mx);
    Sl[n2 * 124 + m] = pv;
    sum += pv;
  }
  #pragma unroll
  for (int ofs = 1; ofs < 8; ofs <<= 1) sum += __shfl_xor(sum, ofs, 64);
  const float rden = 1.f / sum;
  __syncthreads();

  const int ck = sub;
  float oacc[32];
  #pragma unroll
  for (int j = 0; j < 32; ++j) oacc[j] = 0.f;
  const float* prow = &Sl[n2 * 124];
  for (int m = 0; m < 121; ++m){
    float pv = prow[m];
    const bf16x8* vrow = reinterpret_cast<const bf16x8*>(&Vt[m * 256 + ck * 32]);
    #pragma unroll
    for (int q = 0; q < 4; ++q){
      bf16x8 v8 = vrow[q];
      #pragma unroll
      for (int j = 0; j < 8; ++j) oacc[q * 8 + j] = fmaf(pv, (float)v8[j], oacc[q * 8 + j]);
    }
  }
  float s1 = 0.f, s2 = 0.f;
  #pragma unroll
  for (int j = 0; j < 32; ++j){ oacc[j] *= rden; s1 += oacc[j]; s2 += oacc[j] * oacc[j]; }
  #pragma unroll
  for (int ofs = 1; ofs < 8; ofs <<= 1){ s1 += __shfl_xor(s1, ofs, 64); s2 += __shfl_xor(s2, ofs, 64); }
  const float mean = s1 * (1.f / 256.f);
  const float var = s2 * (1.f / 256.f) - mean * mean;
  const float rstd = rsqrtf(var + 1e-5f);
  float g = gammap[0]; g = fminf(fmaxf(g, 0.f), 1.f);

  int nglob = nb0 + n2;
  int srem = nglob - b * 7744;
  int y = srem / 88, x = srem - y * 88;
  size_t pix = ((size_t)(b * 90 + y + 1)) * 90 + (x + 1);
  const unsigned short* res = Xpad + pix * 512 + resChOff + ck * 32;
  unsigned short* outp = FusPad + pix * 576 + outChOff + ck * 32;
  #pragma unroll
  for (int q = 0; q < 4; ++q){
    union { uint4 v; unsigned short s_[8]; } ru, wu;
    ru.v = *reinterpret_cast<const uint4*>(res + q * 8);
    #pragma unroll
    for (int j = 0; j < 8; ++j){
      int c = ck * 32 + q * 8 + j;
      float yv = (oacc[q * 8 + j] - mean) * rstd * ng[c] + nbv[c];
      wu.s_[j] = f2bf(bf2f(ru.s_[j]) + g * yv);
    }
    *reinterpret_cast<uint4*>(outp + q * 8) = wu.v;
  }
}

// ================================================================ host
extern "C" void kernel_launch(void* const* d_in, const int* in_sizes, int n_in,
                              void* d_out, int out_size, void* d_ws, size_t ws_size,
                              hipStream_t stream)
{
  const float* P[42];
  for (int i = 0; i < 42; ++i) P[i] = (const float*)d_in[i];
  // 0 f_rgb 1 f_depth 2 sm_w1 3 sm_b1 4 sm_g1 5 sm_be1 6 sm_m1 7 sm_v1 8 sm_w2 9 sm_b2
  // d2r: 10 q_w 11 q_b 12 k_w 13 k_b 14 v_w 15 v_b 16 sr_w 17 sr_b 18 ln_g 19 ln_b 20 norm_g 21 norm_b
  // r2d: 22..33 same order; 34 d2r_gamma 35 r2d_gamma
  // 36 fus_w 37 fus_b 38 fus_g 39 fus_be 40 fus_m 41 fus_v

  char* ws = (char*)d_ws;
  size_t off = 0;
  auto take = [&](size_t bytes) -> char* {
    char* p = ws + off; off += (bytes + 255) & ~(size_t)255; return p;
  };
  unsigned short* XPAD = (unsigned short*)take(8ull * 8100 * 512 * 2);   // 66.4 MB
  unsigned short* FUSP = (unsigned short*)take(8ull * 8100 * 576 * 2);   // 74.6 MB
  unsigned short* H1   = (unsigned short*)take(61952ull * 256 * 2);      // 31.7 MB
  unsigned short* FDM  = H1;  // alias: h1 is dead after mask_k, fdm written after
  unsigned short* W1T  = (unsigned short*)take(9ull * 256 * 512 * 2);
  unsigned short* WFT  = (unsigned short*)take(9ull * 256 * 576 * 2);
  unsigned short* WSRA = (unsigned short*)take(64ull * 256 * 256 * 2);
  unsigned short* WSRB = (unsigned short*)take(64ull * 256 * 256 * 2);
  float* PART = (float*)take(16ull * 968 * 256 * 4);                      // 15.9 MB
  float* QB   = (float*)take(61952ull * 32 * 4);
  unsigned short* KVR = (unsigned short*)take(968ull * 256 * 2);
  float* KB   = (float*)take(968ull * 32 * 4);
  unsigned short* VB = (unsigned short*)take(968ull * 256 * 2);
  float* MASK = (float*)take(61952ull * 4);
  float* SC1 = (float*)take(256 * 4);
  float* SH1 = (float*)take(256 * 4);
  float* SCF = (float*)take(256 * 4);
  float* SHF = (float*)take(256 * 4);
  (void)ws_size; (void)in_sizes; (void)n_in; (void)out_size;

  hipMemsetAsync(XPAD, 0, 8ull * 8100 * 512 * 2, stream);
  hipMemsetAsync(FUSP, 0, 8ull * 8100 * 576 * 2, stream);

  bnprep_k<<<1, 256, 0, stream>>>(P[4], P[5], P[6], P[7], P[3],
                                  P[38], P[39], P[40], P[41], P[37],
                                  SC1, SH1, SCF, SHF);
  prep_xpad_k<<<7744, 256, 0, stream>>>(P[0], P[1], XPAD);
  prep_w1t_k<<<4608, 256, 0, stream>>>(P[2], W1T);
  prep_wfus_k<<<5184, 256, 0, stream>>>(P[36], WFT);
  prep_wsr_k<<<16384, 256, 0, stream>>>(P[16], WSRA);
  prep_wsr_k<<<16384, 256, 0, stream>>>(P[28], WSRB);

  // conv1 3x3 (512->256) + BN + ReLU -> h1 NHWC bf16
  GemmP g1{};
  g1.A = XPAD; g1.W = W1T; g1.ep_scale = SC1; g1.ep_shift = SH1; g1.out = H1;
  g1.img_px = 8100; g1.row_px = 90; g1.px_el = 512; g1.ch_off = 0; g1.y0 = 0; g1.x0 = 0;
  g1.tapw = 3; g1.stridepix = 1; g1.out_w = 88; g1.out_imgpx = 7744;
  g1.Cin = 512; g1.Mtot = 61952; g1.Mtiles = 484; g1.Ntiles = 2; g1.k_per = 4608;
  gemm_k<0><<<968, 256, 0, stream>>>(g1);

  mask_k<<<242, 256, 0, stream>>>(H1, P[8], P[9], MASK, FUSP);
  fdm_k<<<7744, 256, 0, stream>>>(XPAD, MASK, FDM);

  // ---------------- d2r: Q from f_rgb, KV from f_depth_masked ----------------
  GemmP gs{};
  gs.A = FDM; gs.W = WSRA; gs.out = PART;
  gs.img_px = 7744; gs.row_px = 88; gs.px_el = 256; gs.ch_off = 0; gs.y0 = 0; gs.x0 = 0;
  gs.tapw = 8; gs.stridepix = 8; gs.out_w = 11; gs.out_imgpx = 121;
  gs.Cin = 256; gs.Mtot = 968; gs.Mtiles = 8; gs.Ntiles = 2; gs.k_per = 1024;
  gemm_k<2><<<256, 256, 0, stream>>>(gs);
  lnkvr_k<<<968, 256, 0, stream>>>(PART, P[17], P[18], P[19], KVR);
  dotconv_k<<<7744, 256, 0, stream>>>(XPAD, 1, P[10], P[11], QB);
  dotconv_k<<<121, 256, 0, stream>>>(KVR, 0, P[12], P[13], KB);
  vconv_k<<<968, 256, 0, stream>>>(KVR, P[14], P[15], VB);
  attn_k<<<1936, 256, 0, stream>>>(QB, KB, VB, XPAD, 0, FUSP, 0, P[20], P[21], P[34]);

  // ---------------- r2d: Q from f_depth_masked, KV from f_rgb ----------------
  gs.A = XPAD; gs.W = WSRB;
  gs.img_px = 8100; gs.row_px = 90; gs.px_el = 512; gs.y0 = 1; gs.x0 = 1;
  gemm_k<2><<<256, 256, 0, stream>>>(gs);
  lnkvr_k<<<968, 256, 0, stream>>>(PART, P[29], P[30], P[31], KVR);
  dotconv_k<<<7744, 256, 0, stream>>>(FDM, 0, P[22], P[23], QB);
  dotconv_k<<<121, 256, 0, stream>>>(KVR, 0, P[24], P[25], KB);
  vconv_k<<<968, 256, 0, stream>>>(KVR, P[26], P[27], VB);
  attn_k<<<1936, 256, 0, stream>>>(QB, KB, VB, XPAD, 256, FUSP, 256, P[32], P[33], P[35]);

  // final fused conv 3x3 (576->256) + BN + ReLU -> d_out f32 NCHW
  GemmP gf{};
  gf.A = FUSP; gf.W = WFT; gf.ep_scale = SCF; gf.ep_shift = SHF; gf.out = d_out;
  gf.img_px = 8100; gf.row_px = 90; gf.px_el = 576; gf.ch_off = 0; gf.y0 = 0; gf.x0 = 0;
  gf.tapw = 3; gf.stridepix = 1; gf.out_w = 88; gf.out_imgpx = 7744;
  gf.Cin = 576; gf.Mtot = 61952; gf.Mtiles = 484; gf.Ntiles = 2; gf.k_per = 5184;
  gemm_k<1><<<968, 256, 0, stream>>>(gf);
}

// Round 3
// 1168.884 us; speedup vs baseline: 1.4397x; 1.4397x over previous
//
#include <hip/hip_runtime.h>
#include <hip/hip_bf16.h>

// BiDirectionalFusionModule on MI355X.
// All heavy convs = implicit GEMM, bf16 MFMA 16x16x32, f32 accumulate.
// Activations staged as zero-padded NHWC bf16. ~220MB workspace.
// R2: global_load_lds(16B) GEMM staging; coalesced weight preps;
//     LDS/transposed weights for the 1x1 convs.
// R3: FIX dotconv_k weight staging (was copying only half of wl -> garbage Q/K).

typedef __bf16 bf16x8 __attribute__((ext_vector_type(8)));
typedef float f32x4 __attribute__((ext_vector_type(4)));

#define DEVI __device__ __forceinline__

DEVI float bf2f(unsigned short u){
  union { unsigned int i; float f; } v; v.i = ((unsigned int)u) << 16; return v.f;
}
DEVI unsigned short f2bf(float f){
  union { float f; unsigned int i; } v; v.f = f;
  unsigned int x = v.i;
  unsigned int r = (x + 0x7fffu + ((x >> 16) & 1u)) >> 16;
  return (unsigned short)r;
}

// ---------------------------------------------------------------- BN prep
__global__ void bnprep_k(const float* __restrict__ g1, const float* __restrict__ be1,
                         const float* __restrict__ m1, const float* __restrict__ v1,
                         const float* __restrict__ b1,
                         const float* __restrict__ gf, const float* __restrict__ bef,
                         const float* __restrict__ mf, const float* __restrict__ vf,
                         const float* __restrict__ bf,
                         float* __restrict__ sc1, float* __restrict__ sh1,
                         float* __restrict__ scf, float* __restrict__ shf)
{
  int c = threadIdx.x;
  float s = g1[c] * rsqrtf(v1[c] + 1e-5f);
  sc1[c] = s; sh1[c] = (b1[c] - m1[c]) * s + be1[c];
  s = gf[c] * rsqrtf(vf[c] + 1e-5f);
  scf[c] = s; shf[c] = (bf[c] - mf[c]) * s + bef[c];
}

// ------------------------------------------------- NCHW f32 -> padded NHWC bf16
// Xpad layout: [8][90][90][512], ch 0..255 = rgb, 256..511 = depth. Borders pre-zeroed.
__global__ __launch_bounds__(256)
void prep_xpad_k(const float* __restrict__ rgb, const float* __restrict__ dep,
                 unsigned short* __restrict__ Xpad)
{
  __shared__ unsigned short tile[64][65];
  int bi = blockIdx.x;
  int b = bi / 968;
  int rem = bi - b * 968;
  int cblk = rem / 121;
  int pblk = rem - cblk * 121;
  int t = threadIdx.x;
  int pl = t & 63;
  #pragma unroll
  for (int pass = 0; pass < 16; ++pass){
    int cl = pass * 4 + (t >> 6);
    int c = cblk * 64 + cl;
    const float* sp = (c < 256) ? (rgb + ((size_t)b * 256 + c) * 7744)
                                : (dep + ((size_t)b * 256 + (c - 256)) * 7744);
    tile[cl][pl] = f2bf(sp[pblk * 64 + pl]);
  }
  __syncthreads();
  int cl2 = t & 63;
  for (int pass = 0; pass < 16; ++pass){
    int pl2 = pass * 4 + (t >> 6);
    int pixg = pblk * 64 + pl2;
    int y = pixg / 88, x = pixg - y * 88;
    Xpad[(((size_t)b * 90 + y + 1) * 90 + (x + 1)) * 512 + cblk * 64 + cl2] = tile[cl2][pl2];
  }
}

// ---------------------------------------------------------------- weight reshuffles
// o: [9tap][256co][512ci] bf16 from sm_w1 (256,512,3,3). One block per co; coalesced.
__global__ __launch_bounds__(256)
void prep_w1t_k(const float* __restrict__ w, unsigned short* __restrict__ o)
{
  int co = blockIdx.x, t = threadIdx.x;
  const float* src = w + (size_t)co * 4608 + t * 18;   // ci=2t..2t+1, taps 0..8
  unsigned int* op = (unsigned int*)o;
  #pragma unroll
  for (int k = 0; k < 9; ++k){
    unsigned short lo = f2bf(src[k]);
    unsigned short hi = f2bf(src[9 + k]);
    op[((size_t)k * 256 + co) * 256 + t] = lo | ((unsigned int)hi << 16);
  }
}
// o: [9tap][256co][576ci] from fus_w (256,513,3,3); ci>=513 zero-padded.
__global__ __launch_bounds__(256)
void prep_wfus_k(const float* __restrict__ w, unsigned short* __restrict__ o)
{
  int co = blockIdx.x, t = threadIdx.x;
  const float* src = w + (size_t)co * 4617 + t * 18;   // ci<512 part
  unsigned int* op = (unsigned int*)o;
  #pragma unroll
  for (int k = 0; k < 9; ++k){
    unsigned short lo = f2bf(src[k]);
    unsigned short hi = f2bf(src[9 + k]);
    op[((size_t)k * 256 + co) * 288 + t] = lo | ((unsigned int)hi << 16);
  }
  if (t < 32){
    #pragma unroll
    for (int k = 0; k < 9; ++k){
      unsigned int val = 0;
      if (t == 0) val = (unsigned int)f2bf(w[(size_t)co * 4617 + 512 * 9 + k]); // ci=512
      op[((size_t)k * 256 + co) * 288 + 256 + t] = val;
    }
  }
}
// o: [64tap][256co][256ci] from sr_w (256,256,8,8). One block per co; LDS transpose.
__global__ __launch_bounds__(256)
void prep_wsr_k(const float* __restrict__ w, unsigned short* __restrict__ o)
{
  __shared__ float ld[64][65];
  int co = blockIdx.x;
  int t = threadIdx.x;
  for (int cib = 0; cib < 256; cib += 64){
    int cil = t >> 2, tq = t & 3;
    const float* src = w + ((size_t)co * 256 + cib + cil) * 64 + tq * 16;
    float v[16];
    #pragma unroll
    for (int k = 0; k < 16; ++k) v[k] = src[k];
    __syncthreads();
    #pragma unroll
    for (int k = 0; k < 16; ++k) ld[cil][tq * 16 + k] = v[k];
    __syncthreads();
    #pragma unroll
    for (int tp = 0; tp < 16; ++tp){
      int tap = tp * 4 + (t >> 6);
      int ci = t & 63;
      o[((size_t)tap * 256 + co) * 256 + cib + ci] = f2bf(ld[ci][tap]);
    }
  }
}
// generic (R,C) f32 -> [C][R] bf16 transpose (R,C multiples of 32)
__global__ __launch_bounds__(256)
void tranw_k(const float* __restrict__ in, unsigned short* __restrict__ out, int R, int C)
{
  __shared__ float tl[32][33];
  int tiles_c = C >> 5;
  int tr = (blockIdx.x / tiles_c) << 5, tc = (blockIdx.x % tiles_c) << 5;
  int t = threadIdx.x; int r = t >> 5, c = t & 31;
  #pragma unroll
  for (int p = 0; p < 4; ++p)
    tl[r + p * 8][c] = in[(size_t)(tr + r + p * 8) * C + tc + c];
  __syncthreads();
  #pragma unroll
  for (int p = 0; p < 4; ++p)
    out[(size_t)(tc + r + p * 8) * R + tr + c] = f2bf(tl[c][r + p * 8]);
}

// ---------------------------------------------------------------- implicit GEMM
// C[n][co] = sum_{tap,ci} A[pixel(n,tap)][ci] * W[tap][co][ci]
// 128x128 tile, BK=64, 4 waves (2x2), mfma 16x16x32 bf16, XOR-swizzled LDS,
// staging via global_load_lds width-16 (pre-swizzled global source, linear LDS dest).
struct GemmP {
  const unsigned short* A;
  const unsigned short* W;
  const float* ep_scale;
  const float* ep_shift;
  void* out;
  int img_px, row_px, px_el, ch_off, y0, x0;
  int tapw, stridepix, out_w, out_imgpx;
  int Cin, Mtot, Mtiles, Ntiles, k_per;
};

template<int EPI>   // 0: BN+ReLU -> bf16 NHWC[.][256]   1: BN+ReLU -> f32 NCHW   2: f32 partial [slot][968][256]
__global__ __launch_bounds__(256)
void gemm_k(GemmP p)
{
  __shared__ __bf16 As[128 * 64];
  __shared__ __bf16 Bs[128 * 64];
  const int t = threadIdx.x;
  const int lane = t & 63;
  const int wid = t >> 6;
  const int wr = wid >> 1, wc = wid & 1;

  int pid = blockIdx.x;
  int mt = pid % p.Mtiles;
  int nt = (pid / p.Mtiles) % p.Ntiles;
  int slot = pid / (p.Mtiles * p.Ntiles);
  int kb = slot * p.k_per;
  int tap0 = kb / p.Cin;        // host guarantees k_per % Cin == 0, kb % Cin == 0
  int ntap = p.k_per / p.Cin;

  long long apix[4]; int cbg8[4]; int wrow[4];
  #pragma unroll
  for (int i = 0; i < 4; ++i){
    int r = i * 32 + (t >> 3);
    cbg8[i] = ((t & 7) ^ (r & 7)) * 8;
    int n = mt * 128 + r;
    int nc = n < p.Mtot ? n : 0;
    int b = nc / p.out_imgpx; int rr = nc - b * p.out_imgpx;
    int yo = rr / p.out_w;    int xo = rr - yo * p.out_w;
    apix[i] = (long long)b * p.img_px + (long long)(yo * p.stridepix + p.y0) * p.row_px
            + (xo * p.stridepix + p.x0);
    wrow[i] = (nt * 128 + r) * p.Cin + cbg8[i];
  }

  f32x4 acc[4][4];
  #pragma unroll
  for (int i = 0; i < 4; ++i)
    #pragma unroll
    for (int j = 0; j < 4; ++j)
      acc[i][j] = f32x4{0.f, 0.f, 0.f, 0.f};

  const long long wstap = 256LL * p.Cin;

  for (int tp = 0; tp < ntap; ++tp){
    int tap = tap0 + tp;
    int dy = tap / p.tapw, dx = tap - dy * p.tapw;
    const unsigned short* wb = p.W + (long long)tap * wstap;
    long long abase[4];
    #pragma unroll
    for (int i = 0; i < 4; ++i)
      abase[i] = (apix[i] + (long long)dy * p.row_px + dx) * p.px_el + p.ch_off + cbg8[i];

    for (int cib = 0; cib < p.Cin; cib += 64){
      __syncthreads();
      #pragma unroll
      for (int i = 0; i < 4; ++i){
        __builtin_amdgcn_global_load_lds(
            (__attribute__((address_space(1))) void*)(p.A + abase[i] + cib),
            (__attribute__((address_space(3))) void*)(&As[i * 2048 + wid * 512]),
            16, 0, 0);
        __builtin_amdgcn_global_load_lds(
            (__attribute__((address_space(1))) void*)(wb + wrow[i] + cib),
            (__attribute__((address_space(3))) void*)(&Bs[i * 2048 + wid * 512]),
            16, 0, 0);
      }
      __syncthreads();
      #pragma unroll
      for (int ks = 0; ks < 2; ++ks){
        bf16x8 av[4], bv[4];
        #pragma unroll
        for (int mi = 0; mi < 4; ++mi){
          int ar = wr * 64 + mi * 16 + (lane & 15);
          int cb = (ks * 4 + (lane >> 4)) ^ (ar & 7);
          av[mi] = *reinterpret_cast<const bf16x8*>(&As[ar * 64 + cb * 8]);
        }
        #pragma unroll
        for (int ni = 0; ni < 4; ++ni){
          int br = wc * 64 + ni * 16 + (lane & 15);
          int cb = (ks * 4 + (lane >> 4)) ^ (br & 7);
          bv[ni] = *reinterpret_cast<const bf16x8*>(&Bs[br * 64 + cb * 8]);
        }
        #pragma unroll
        for (int mi = 0; mi < 4; ++mi)
          #pragma unroll
          for (int ni = 0; ni < 4; ++ni)
            acc[mi][ni] = __builtin_amdgcn_mfma_f32_16x16x32_bf16(av[mi], bv[ni], acc[mi][ni], 0, 0, 0);
      }
    }
  }

  const int r0 = (lane >> 4) * 4;
  const int c0 = lane & 15;
  #pragma unroll
  for (int mi = 0; mi < 4; ++mi){
    int nbase = mt * 128 + wr * 64 + mi * 16 + r0;
    #pragma unroll
    for (int ni = 0; ni < 4; ++ni){
      int co = nt * 128 + wc * 64 + ni * 16 + c0;
      f32x4 a = acc[mi][ni];
      if constexpr (EPI == 0){
        float sc = p.ep_scale[co], sh = p.ep_shift[co];
        unsigned short* o = (unsigned short*)p.out;
        #pragma unroll
        for (int r = 0; r < 4; ++r){
          float v = fmaf(a[r], sc, sh); v = v > 0.f ? v : 0.f;
          o[(size_t)(nbase + r) * 256 + co] = f2bf(v);
        }
      } else if constexpr (EPI == 1){
        float sc = p.ep_scale[co], sh = p.ep_shift[co];
        float* o = (float*)p.out;
        int b = nbase / 7744; int s = nbase - b * 7744;
        float4 v;
        v.x = fmaxf(fmaf(a[0], sc, sh), 0.f);
        v.y = fmaxf(fmaf(a[1], sc, sh), 0.f);
        v.z = fmaxf(fmaf(a[2], sc, sh), 0.f);
        v.w = fmaxf(fmaf(a[3], sc, sh), 0.f);
        *reinterpret_cast<float4*>(o + ((size_t)(b * 256 + co)) * 7744 + s) = v;
      } else {
        float* o = (float*)p.out + (size_t)slot * 968 * 256;
        #pragma unroll
        for (int r = 0; r < 4; ++r){
          int n = nbase + r;
          if (n < p.Mtot) o[(size_t)n * 256 + co] = a[r];
        }
      }
    }
  }
}

// ---------------------------------------------------------------- spatial mask
__global__ __launch_bounds__(256)
void mask_k(const unsigned short* __restrict__ h1, const float* __restrict__ w2,
            const float* __restrict__ b2, float* __restrict__ mask,
            unsigned short* __restrict__ FusPad)
{
  __shared__ float w[256];
  int t = threadIdx.x;
  w[t] = w2[t];
  __syncthreads();
  int n = blockIdx.x * 256 + t;
  const unsigned short* row = h1 + (size_t)n * 256;
  float s = b2[0];
  for (int c = 0; c < 256; c += 8){
    union { uint4 v; unsigned short s_[8]; } u;
    u.v = *reinterpret_cast<const uint4*>(row + c);
    #pragma unroll
    for (int j = 0; j < 8; ++j) s = fmaf(bf2f(u.s_[j]), w[c + j], s);
  }
  float m = 1.f / (1.f + __expf(-s));
  mask[n] = m;
  int b = n / 7744, sr = n - b * 7744;
  int y = sr / 88, x = sr - y * 88;
  FusPad[(((size_t)b * 90 + y + 1) * 90 + (x + 1)) * 576 + 512] = f2bf(m);
}

// ---------------------------------------------------------------- f_depth * mask -> NHWC bf16 [61952][256]
__global__ __launch_bounds__(256)
void fdm_k(const unsigned short* __restrict__ Xpad, const float* __restrict__ mask,
           unsigned short* __restrict__ fdm)
{
  int idx = blockIdx.x * 256 + threadIdx.x;   // 61952*32
  int n = idx >> 5, cb = idx & 31;
  int b = n / 7744, s = n - b * 7744;
  int y = s / 88, x = s - y * 88;
  size_t pix = ((size_t)(b * 90 + y + 1)) * 90 + x + 1;
  union { uint4 v; unsigned short s_[8]; } u, w;
  u.v = *reinterpret_cast<const uint4*>(Xpad + pix * 512 + 256 + cb * 8);
  float m = mask[n];
  #pragma unroll
  for (int j = 0; j < 8; ++j) w.s_[j] = f2bf(bf2f(u.s_[j]) * m);
  *reinterpret_cast<uint4*>(fdm + (size_t)n * 256 + cb * 8) = w.v;
}

// ---------------------------------------------------------------- sum split-K partials + channel LN -> kvr bf16
__global__ __launch_bounds__(256)
void lnkvr_k(const float* __restrict__ part, const float* __restrict__ srb,
             const float* __restrict__ lng, const float* __restrict__ lnb,
             unsigned short* __restrict__ kvr)
{
  int n = blockIdx.x, t = threadIdx.x;
  float v = srb[t];
  for (int s = 0; s < 16; ++s) v += part[((size_t)s * 968 + n) * 256 + t];
  float s1 = v, s2 = v * v;
  #pragma unroll
  for (int o = 1; o < 64; o <<= 1){ s1 += __shfl_xor(s1, o, 64); s2 += __shfl_xor(s2, o, 64); }
  __shared__ float a1[4], a2[4];
  if ((t & 63) == 0){ a1[t >> 6] = s1; a2[t >> 6] = s2; }
  __syncthreads();
  float t1 = a1[0] + a1[1] + a1[2] + a1[3];
  float t2 = a2[0] + a2[1] + a2[2] + a2[3];
  float mean = t1 * (1.f / 256.f);
  float var = t2 * (1.f / 256.f) - mean * mean;
  float rstd = rsqrtf(var + 1e-5f);
  kvr[(size_t)n * 256 + t] = f2bf((v - mean) * rstd * lng[t] + lnb[t]);
}

// ---------------------------------------------------------------- 1x1 conv 256->32 (Q and K)
// wt: [256 ci][32 co] bf16 (pre-transposed). Weights staged in LDS (full 16KB!).
// mode 0: src = linear bf16 [n][256].  mode 1: src = Xpad interior, rgb channels.
__global__ __launch_bounds__(256)
void dotconv_k(const unsigned short* __restrict__ src, int mode,
               const unsigned short* __restrict__ wt, const float* __restrict__ bias,
               float* __restrict__ out)
{
  __shared__ unsigned short wl[256 * 32];
  const int t = threadIdx.x;
  {
    uint4* d = (uint4*)wl; const uint4* s = (const uint4*)wt;
    #pragma unroll
    for (int k = 0; k < 4; ++k) d[t + 256 * k] = s[t + 256 * k];   // 1024 uint4 = all of wl
  }
  __syncthreads();
  const int n = blockIdx.x * 8 + (t >> 5);
  const int co = t & 31;
  const unsigned short* row;
  if (mode == 1){
    int b = n / 7744, s2 = n - b * 7744;
    int y = s2 / 88, x = s2 - y * 88;
    row = src + (((size_t)(b * 90 + y + 1)) * 90 + (x + 1)) * 512;
  } else {
    row = src + (size_t)n * 256;
  }
  float sum = bias[co];
  for (int c = 0; c < 256; c += 8){
    union { uint4 v; unsigned short s_[8]; } u;
    u.v = *reinterpret_cast<const uint4*>(row + c);
    #pragma unroll
    for (int j = 0; j < 8; ++j)
      sum = fmaf(bf2f(u.s_[j]), bf2f(wl[(c + j) * 32 + co]), sum);
  }
  out[(size_t)n * 32 + co] = sum;
}

// ---------------------------------------------------------------- 1x1 conv 256->256 (V)
// vwt: [256 ci][256 co] bf16 (pre-transposed, coalesced reads, L2-resident)
__global__ __launch_bounds__(256)
void vconv_k(const unsigned short* __restrict__ kvr, const unsigned short* __restrict__ vwt,
             const float* __restrict__ vb, unsigned short* __restrict__ V)
{
  __shared__ float rowf[256];
  const int n = blockIdx.x, t = threadIdx.x;
  rowf[t] = bf2f(kvr[(size_t)n * 256 + t]);
  __syncthreads();
  float sum = vb[t];
  #pragma unroll 8
  for (int c = 0; c < 256; ++c)
    sum = fmaf(rowf[c], bf2f(vwt[(size_t)c * 256 + t]), sum);
  V[(size_t)n * 256 + t] = f2bf(sum);
}

// ---------------------------------------------------------------- fused attention + LN + residual
__global__ __launch_bounds__(256)
void attn_k(const float* __restrict__ Qbuf, const float* __restrict__ Kbuf,
            const unsigned short* __restrict__ Vbuf,
            const unsigned short* __restrict__ Xpad, int resChOff,
            unsigned short* __restrict__ FusPad, int outChOff,
            const float* __restrict__ ng, const float* __restrict__ nbv,
            const float* __restrict__ gammap)
{
  __shared__ float Kt[121 * 33];
  __shared__ float Qt[32 * 33];
  __shared__ float Sl[32 * 124];
  __shared__ unsigned short Vt[121 * 256];
  const int t = threadIdx.x;
  const int nb0 = blockIdx.x * 32;
  const int b = nb0 / 7744;
  const int mbase = b * 121;

  {
    const float4* src = reinterpret_cast<const float4*>(Qbuf + (size_t)nb0 * 32);
    float4 v = src[t];
    int i = t >> 3, c = (t & 7) * 4;
    float* q = &Qt[i * 33 + c];
    q[0] = v.x; q[1] = v.y; q[2] = v.z; q[3] = v.w;
  }
  for (int idx = t; idx < 121 * 32; idx += 256){
    int m = idx >> 5, c = idx & 31;
    Kt[m * 33 + c] = Kbuf[(size_t)mbase * 32 + idx];
  }
  {
    const uint4* src = reinterpret_cast<const uint4*>(Vbuf + (size_t)mbase * 256);
    uint4* dst = reinterpret_cast<uint4*>(Vt);
    for (int idx = t; idx < 121 * 32; idx += 256) dst[idx] = src[idx];
  }
  __syncthreads();

  const float scale = 0.17677669529663687f;  // 32^-0.5
  for (int it = 0; it < 16; ++it){
    int idx = it * 256 + t;
    int n = idx >> 7, m = idx & 127;
    if (m < 121){
      const float* qp = &Qt[n * 33];
      const float* kp = &Kt[m * 33];
      float s = 0.f;
      #pragma unroll
      for (int c = 0; c < 32; ++c) s = fmaf(qp[c], kp[c], s);
      Sl[n * 124 + m] = s * scale;
    }
  }
  __syncthreads();

  const int n2 = t >> 3, sub = t & 7;
  float mx = -1e30f;
  for (int m = sub; m < 121; m += 8) mx = fmaxf(mx, Sl[n2 * 124 + m]);
  #pragma unroll
  for (int ofs = 1; ofs < 8; ofs <<= 1) mx = fmaxf(mx, __shfl_xor(mx, ofs, 64));
  float sum = 0.f;
  for (int m = sub; m < 121; m += 8){
    float pv = __expf(Sl[n2 * 124 + m] - mx);
    Sl[n2 * 124 + m] = pv;
    sum += pv;
  }
  #pragma unroll
  for (int ofs = 1; ofs < 8; ofs <<= 1) sum += __shfl_xor(sum, ofs, 64);
  const float rden = 1.f / sum;
  __syncthreads();

  const int ck = sub;
  float oacc[32];
  #pragma unroll
  for (int j = 0; j < 32; ++j) oacc[j] = 0.f;
  const float* prow = &Sl[n2 * 124];
  for (int m = 0; m < 121; ++m){
    float pv = prow[m];
    const bf16x8* vrow = reinterpret_cast<const bf16x8*>(&Vt[m * 256 + ck * 32]);
    #pragma unroll
    for (int q = 0; q < 4; ++q){
      bf16x8 v8 = vrow[q];
      #pragma unroll
      for (int j = 0; j < 8; ++j) oacc[q * 8 + j] = fmaf(pv, (float)v8[j], oacc[q * 8 + j]);
    }
  }
  float s1 = 0.f, s2 = 0.f;
  #pragma unroll
  for (int j = 0; j < 32; ++j){ oacc[j] *= rden; s1 += oacc[j]; s2 += oacc[j] * oacc[j]; }
  #pragma unroll
  for (int ofs = 1; ofs < 8; ofs <<= 1){ s1 += __shfl_xor(s1, ofs, 64); s2 += __shfl_xor(s2, ofs, 64); }
  const float mean = s1 * (1.f / 256.f);
  const float var = s2 * (1.f / 256.f) - mean * mean;
  const float rstd = rsqrtf(var + 1e-5f);
  float g = gammap[0]; g = fminf(fmaxf(g, 0.f), 1.f);

  int nglob = nb0 + n2;
  int srem = nglob - b * 7744;
  int y = srem / 88, x = srem - y * 88;
  size_t pix = ((size_t)(b * 90 + y + 1)) * 90 + (x + 1);
  const unsigned short* res = Xpad + pix * 512 + resChOff + ck * 32;
  unsigned short* outp = FusPad + pix * 576 + outChOff + ck * 32;
  #pragma unroll
  for (int q = 0; q < 4; ++q){
    union { uint4 v; unsigned short s_[8]; } ru, wu;
    ru.v = *reinterpret_cast<const uint4*>(res + q * 8);
    #pragma unroll
    for (int j = 0; j < 8; ++j){
      int c = ck * 32 + q * 8 + j;
      float yv = (oacc[q * 8 + j] - mean) * rstd * ng[c] + nbv[c];
      wu.s_[j] = f2bf(bf2f(ru.s_[j]) + g * yv);
    }
    *reinterpret_cast<uint4*>(outp + q * 8) = wu.v;
  }
}

// ================================================================ host
extern "C" void kernel_launch(void* const* d_in, const int* in_sizes, int n_in,
                              void* d_out, int out_size, void* d_ws, size_t ws_size,
                              hipStream_t stream)
{
  const float* P[42];
  for (int i = 0; i < 42; ++i) P[i] = (const float*)d_in[i];

  char* ws = (char*)d_ws;
  size_t off = 0;
  auto take = [&](size_t bytes) -> char* {
    char* p = ws + off; off += (bytes + 255) & ~(size_t)255; return p;
  };
  unsigned short* XPAD = (unsigned short*)take(8ull * 8100 * 512 * 2);   // 66.4 MB
  unsigned short* FUSP = (unsigned short*)take(8ull * 8100 * 576 * 2);   // 74.6 MB
  unsigned short* H1   = (unsigned short*)take(61952ull * 256 * 2);      // 31.7 MB
  unsigned short* FDM  = H1;  // alias: h1 dead after mask_k
  unsigned short* W1T  = (unsigned short*)take(9ull * 256 * 512 * 2);
  unsigned short* WFT  = (unsigned short*)take(9ull * 256 * 576 * 2);
  unsigned short* WSRA = (unsigned short*)take(64ull * 256 * 256 * 2);
  unsigned short* WSRB = (unsigned short*)take(64ull * 256 * 256 * 2);
  float* PART = (float*)take(16ull * 968 * 256 * 4);                      // 15.9 MB
  float* QB   = (float*)take(61952ull * 32 * 4);
  unsigned short* KVR = (unsigned short*)take(968ull * 256 * 2);
  float* KB   = (float*)take(968ull * 32 * 4);
  unsigned short* VB = (unsigned short*)take(968ull * 256 * 2);
  float* MASK = (float*)take(61952ull * 4);
  float* SC1 = (float*)take(256 * 4);
  float* SH1 = (float*)take(256 * 4);
  float* SCF = (float*)take(256 * 4);
  float* SHF = (float*)take(256 * 4);
  unsigned short* QWTA = (unsigned short*)take(256ull * 32 * 2);
  unsigned short* KWTA = (unsigned short*)take(256ull * 32 * 2);
  unsigned short* VWTA = (unsigned short*)take(256ull * 256 * 2);
  unsigned short* QWTB = (unsigned short*)take(256ull * 32 * 2);
  unsigned short* KWTB = (unsigned short*)take(256ull * 32 * 2);
  unsigned short* VWTB = (unsigned short*)take(256ull * 256 * 2);
  (void)ws_size; (void)in_sizes; (void)n_in; (void)out_size;

  hipMemsetAsync(XPAD, 0, 8ull * 8100 * 512 * 2, stream);
  hipMemsetAsync(FUSP, 0, 8ull * 8100 * 576 * 2, stream);

  bnprep_k<<<1, 256, 0, stream>>>(P[4], P[5], P[6], P[7], P[3],
                                  P[38], P[39], P[40], P[41], P[37],
                                  SC1, SH1, SCF, SHF);
  prep_xpad_k<<<7744, 256, 0, stream>>>(P[0], P[1], XPAD);
  prep_w1t_k<<<256, 256, 0, stream>>>(P[2], W1T);
  prep_wfus_k<<<256, 256, 0, stream>>>(P[36], WFT);
  prep_wsr_k<<<256, 256, 0, stream>>>(P[16], WSRA);
  prep_wsr_k<<<256, 256, 0, stream>>>(P[28], WSRB);
  tranw_k<<<8, 256, 0, stream>>>(P[10], QWTA, 32, 256);
  tranw_k<<<8, 256, 0, stream>>>(P[12], KWTA, 32, 256);
  tranw_k<<<64, 256, 0, stream>>>(P[14], VWTA, 256, 256);
  tranw_k<<<8, 256, 0, stream>>>(P[22], QWTB, 32, 256);
  tranw_k<<<8, 256, 0, stream>>>(P[24], KWTB, 32, 256);
  tranw_k<<<64, 256, 0, stream>>>(P[26], VWTB, 256, 256);

  // conv1 3x3 (512->256) + BN + ReLU -> h1 NHWC bf16
  GemmP g1{};
  g1.A = XPAD; g1.W = W1T; g1.ep_scale = SC1; g1.ep_shift = SH1; g1.out = H1;
  g1.img_px = 8100; g1.row_px = 90; g1.px_el = 512; g1.ch_off = 0; g1.y0 = 0; g1.x0 = 0;
  g1.tapw = 3; g1.stridepix = 1; g1.out_w = 88; g1.out_imgpx = 7744;
  g1.Cin = 512; g1.Mtot = 61952; g1.Mtiles = 484; g1.Ntiles = 2; g1.k_per = 4608;
  gemm_k<0><<<968, 256, 0, stream>>>(g1);

  mask_k<<<242, 256, 0, stream>>>(H1, P[8], P[9], MASK, FUSP);
  fdm_k<<<7744, 256, 0, stream>>>(XPAD, MASK, FDM);

  // ---------------- d2r: Q from f_rgb, KV from f_depth_masked ----------------
  GemmP gs{};
  gs.A = FDM; gs.W = WSRA; gs.out = PART;
  gs.img_px = 7744; gs.row_px = 88; gs.px_el = 256; gs.ch_off = 0; gs.y0 = 0; gs.x0 = 0;
  gs.tapw = 8; gs.stridepix = 8; gs.out_w = 11; gs.out_imgpx = 121;
  gs.Cin = 256; gs.Mtot = 968; gs.Mtiles = 8; gs.Ntiles = 2; gs.k_per = 1024;
  gemm_k<2><<<256, 256, 0, stream>>>(gs);
  lnkvr_k<<<968, 256, 0, stream>>>(PART, P[17], P[18], P[19], KVR);
  dotconv_k<<<7744, 256, 0, stream>>>(XPAD, 1, QWTA, P[11], QB);
  dotconv_k<<<121, 256, 0, stream>>>(KVR, 0, KWTA, P[13], KB);
  vconv_k<<<968, 256, 0, stream>>>(KVR, VWTA, P[15], VB);
  attn_k<<<1936, 256, 0, stream>>>(QB, KB, VB, XPAD, 0, FUSP, 0, P[20], P[21], P[34]);

  // ---------------- r2d: Q from f_depth_masked, KV from f_rgb ----------------
  gs.A = XPAD; gs.W = WSRB;
  gs.img_px = 8100; gs.row_px = 90; gs.px_el = 512; gs.y0 = 1; gs.x0 = 1;
  gemm_k<2><<<256, 256, 0, stream>>>(gs);
  lnkvr_k<<<968, 256, 0, stream>>>(PART, P[29], P[30], P[31], KVR);
  dotconv_k<<<7744, 256, 0, stream>>>(FDM, 0, QWTB, P[23], QB);
  dotconv_k<<<121, 256, 0, stream>>>(KVR, 0, KWTB, P[25], KB);
  vconv_k<<<968, 256, 0, stream>>>(KVR, VWTB, P[27], VB);
  attn_k<<<1936, 256, 0, stream>>>(QB, KB, VB, XPAD, 256, FUSP, 256, P[32], P[33], P[35]);

  // final fused conv 3x3 (576->256) + BN + ReLU -> d_out f32 NCHW
  GemmP gf{};
  gf.A = FUSP; gf.W = WFT; gf.ep_scale = SCF; gf.ep_shift = SHF; gf.out = d_out;
  gf.img_px = 8100; gf.row_px = 90; gf.px_el = 576; gf.ch_off = 0; gf.y0 = 0; gf.x0 = 0;
  gf.tapw = 3; gf.stridepix = 1; gf.out_w = 88; gf.out_imgpx = 7744;
  gf.Cin = 576; gf.Mtot = 61952; gf.Mtiles = 484; gf.Ntiles = 2; gf.k_per = 5184;
  gemm_k<1><<<968, 256, 0, stream>>>(gf);
}